// Round 2
// baseline (9815.790 us; speedup 1.0000x reference)
//
#include <hip/hip_runtime.h>
#include <cstdint>
#include <cstddef>

// Problem constants (AugmentedLstm: B=64, T=512, D=512, H=512)
#define BB 64
#define TT 512
#define DD 512
#define HH 512
#define SIXH 3072

typedef __attribute__((ext_vector_type(8))) short bf16x8;
typedef __attribute__((ext_vector_type(4))) float f32x4;

// ---- ws layout (byte offsets, 256-aligned) --------------------------------
// flags[0]: 1 if float inputs are fp32 (else bf16); flags[1]: 1 if lengths int64
#define WS_FLAGS 0u
#define WS_H     256u            // 2 x [BB][HH] ushort (bf16 h ping-pong) = 131072 B
#define WS_C     131328u         // [BB][HH] float c                      = 131072 B
#define WS_PS    262400u         // [5][BB][HH] float ps                  = 655360 B
#define WS_PROJ  917760u         // proj chunk: Tc*BB rows x SIXH bf16

__device__ __forceinline__ float bf2f(unsigned short u) {
    union { unsigned int i; float f; } v; v.i = ((unsigned int)u) << 16; return v.f;
}
__device__ __forceinline__ unsigned short f2bf(float f) {
    union { unsigned int i; float f; } v; v.f = f;
    unsigned int r = v.i + 0x7FFFu + ((v.i >> 16) & 1u);  // RNE
    return (unsigned short)(r >> 16);
}
__device__ __forceinline__ float sigm(float x) { return 1.0f / (1.0f + __expf(-x)); }

__device__ __forceinline__ bf16x8 cvt8(const float* p) {
    bf16x8 o;
#pragma unroll
    for (int i = 0; i < 8; i++) o[i] = (short)f2bf(p[i]);
    return o;
}

// ---------------------------------------------------------------------------
// Detect input dtypes from raw bits (runs every call; flags live in ws).
// fp32 data read as bf16: low-half ushorts have uniform-random exponents ->
// ~45% of them have |value| > 1e4. bf16 N(0,1) data: essentially none do.
// int64 lengths: odd int32 words are high words = 0 (values <= 512); int32
// lengths: odd words are real lengths >= 1.
// ---------------------------------------------------------------------------
__global__ void detect_kernel(const unsigned short* __restrict__ x16,
                              const int* __restrict__ len32,
                              int* __restrict__ flags) {
    if (threadIdx.x == 0 && blockIdx.x == 0) {
        int bad = 0;
        for (int i = 0; i < 256; i++) {
            float a = fabsf(bf2f(x16[i]));
            if (a > 1e4f) bad++;
        }
        flags[0] = (bad >= 16) ? 1 : 0;
        flags[1] = (len32[1] == 0 && len32[3] == 0 && len32[5] == 0) ? 1 : 0;
    }
}

// ---------------------------------------------------------------------------
// Proj chunk GEMM: projc[b][tl][0:6H] = x[b][t0+tl][:] @ w_in^T + b_in
// Chunk covers tl in [0,Tc); chunk rows ordered m_local = b*Tc + tl.
// Block: 256 thr = 4 waves; block tile 64(M)x64(N); wave tile 32x32 (2x2 MFMA).
// MFMA 16x16x32 bf16 layouts (verified m89/m91):
//   A: lane holds A[m0+(lane&15)][k0+(lane>>4)*8+j]; B: Bt[n0+(lane&15)][...]
//   D: reg r -> D[m0+(lane>>4)*4+r][n0+(lane&15)]
// ---------------------------------------------------------------------------
template<int FP32>
__device__ __forceinline__ void proj_core(const void* __restrict__ xv,
                                          const void* __restrict__ wv,
                                          const void* __restrict__ bv,
                                          unsigned short* __restrict__ projc,
                                          int t0, int tc_shift) {
    const int tid  = threadIdx.x;
    const int wave = tid >> 6;
    const int lane = tid & 63;
    const int q    = lane >> 4;
    const int r    = lane & 15;

    const int m_blk = blockIdx.y * 64 + (wave >> 1) * 32;   // chunk-local row base
    const int n_blk = blockIdx.x * 64 + (wave & 1) * 32;
    const int Tc    = 1 << tc_shift;
    const int b     = m_blk >> tc_shift;                    // Tc >= 64 => uniform per 32-row group
    const int tl    = m_blk & (Tc - 1);

    const size_t xrow0 = (size_t)(b * TT + t0 + tl + r) * DD;
    const size_t xrow1 = (size_t)(b * TT + t0 + tl + 16 + r) * DD;
    const size_t wrow0 = (size_t)(n_blk + r) * DD;
    const size_t wrow1 = (size_t)(n_blk + 16 + r) * DD;

    f32x4 acc[2][2] = {};
    const int koff = q * 8;
    for (int k0 = 0; k0 < DD; k0 += 32) {
        bf16x8 a0, a1, b0, b1;
        const int k = k0 + koff;
        if (FP32) {
            const float* xf = (const float*)xv;
            const float* wf = (const float*)wv;
            a0 = cvt8(xf + xrow0 + k);  a1 = cvt8(xf + xrow1 + k);
            b0 = cvt8(wf + wrow0 + k);  b1 = cvt8(wf + wrow1 + k);
        } else {
            const unsigned short* xb = (const unsigned short*)xv;
            const unsigned short* wb = (const unsigned short*)wv;
            a0 = *(const bf16x8*)(xb + xrow0 + k);  a1 = *(const bf16x8*)(xb + xrow1 + k);
            b0 = *(const bf16x8*)(wb + wrow0 + k);  b1 = *(const bf16x8*)(wb + wrow1 + k);
        }
        acc[0][0] = __builtin_amdgcn_mfma_f32_16x16x32_bf16(a0, b0, acc[0][0], 0, 0, 0);
        acc[0][1] = __builtin_amdgcn_mfma_f32_16x16x32_bf16(a0, b1, acc[0][1], 0, 0, 0);
        acc[1][0] = __builtin_amdgcn_mfma_f32_16x16x32_bf16(a1, b0, acc[1][0], 0, 0, 0);
        acc[1][1] = __builtin_amdgcn_mfma_f32_16x16x32_bf16(a1, b1, acc[1][1], 0, 0, 0);
    }

#pragma unroll
    for (int mi = 0; mi < 2; mi++) {
#pragma unroll
        for (int ni = 0; ni < 2; ni++) {
            const int n = n_blk + ni * 16 + r;
            const float bias = FP32 ? ((const float*)bv)[n] : bf2f(((const unsigned short*)bv)[n]);
#pragma unroll
            for (int rr = 0; rr < 4; rr++) {
                const int m = m_blk + mi * 16 + q * 4 + rr;
                projc[(size_t)m * SIXH + n] = f2bf(acc[mi][ni][rr] + bias);
            }
        }
    }
}

__global__ __launch_bounds__(256) void proj_kernel(const void* xv, const void* wv, const void* bv,
                                                   unsigned short* projc, const int* flags,
                                                   int t0, int tc_shift) {
    if (flags[0]) proj_core<1>(xv, wv, bv, projc, t0, tc_shift);
    else          proj_core<0>(xv, wv, bv, projc, t0, tc_shift);
}

// ---------------------------------------------------------------------------
// Per-step ps GEMM: ps[g][b][j] = sum_k h[b][k] * w_state[g*H + j][k]
// Grid (8 jblk, 5 g), block 256 = 4 waves; wave computes [64(b) x 16(j)].
// h is carried as bf16 [BB][HH] in ws (ping-pong).
// ---------------------------------------------------------------------------
template<int FP32>
__device__ __forceinline__ void ps_core(const unsigned short* __restrict__ h,
                                        const void* __restrict__ wv,
                                        float* __restrict__ ps) {
    const int tid  = threadIdx.x;
    const int wave = tid >> 6;
    const int lane = tid & 63;
    const int q    = lane >> 4;
    const int r    = lane & 15;
    const int g    = blockIdx.y;
    const int jblk = blockIdx.x;

    const int n0   = jblk * 64 + wave * 16;
    const size_t wrow = (size_t)(g * HH + n0 + r) * HH;

    f32x4 acc[4] = {};
    for (int k0 = 0; k0 < HH; k0 += 32) {
        const int k = k0 + q * 8;
        bf16x8 bw;
        if (FP32) bw = cvt8((const float*)wv + wrow + k);
        else      bw = *(const bf16x8*)((const unsigned short*)wv + wrow + k);
#pragma unroll
        for (int mi = 0; mi < 4; mi++) {
            bf16x8 a = *(const bf16x8*)(h + (size_t)(mi * 16 + r) * HH + k);
            acc[mi] = __builtin_amdgcn_mfma_f32_16x16x32_bf16(a, bw, acc[mi], 0, 0, 0);
        }
    }
#pragma unroll
    for (int mi = 0; mi < 4; mi++) {
#pragma unroll
        for (int rr = 0; rr < 4; rr++) {
            const int bidx = mi * 16 + q * 4 + rr;           // batch
            ps[(size_t)(g * BB + bidx) * HH + n0 + r] = acc[mi][rr];
        }
    }
}

__global__ __launch_bounds__(256) void ps_kernel(const unsigned short* h, const void* wv,
                                                 float* ps, const int* flags) {
    if (flags[0]) ps_core<1>(h, wv, ps);
    else          ps_core<0>(h, wv, ps);
}

// ---------------------------------------------------------------------------
// Per-step epilogue: gates + mask + state update. Grid BB blocks x HH threads.
// ---------------------------------------------------------------------------
template<int FP32, int I64>
__device__ __forceinline__ void epi_core(const float* __restrict__ ps,
                                         const unsigned short* __restrict__ projc,
                                         const void* __restrict__ bsv,
                                         const int* __restrict__ len32,
                                         float* __restrict__ cbuf,
                                         unsigned short* __restrict__ hnext,
                                         void* __restrict__ outv,
                                         int t, int tl, int Tc) {
    const int b = blockIdx.x;
    const int j = threadIdx.x;
    const int len = I64 ? len32[2 * b] : len32[b];

    const size_t pbase = ((size_t)b * Tc + tl) * SIXH + j;
    float pi[6];
#pragma unroll
    for (int g = 0; g < 6; g++) pi[g] = bf2f(projc[pbase + g * HH]);

    float psv[5];
#pragma unroll
    for (int g = 0; g < 5; g++) {
        const float bias = FP32 ? ((const float*)bsv)[g * HH + j]
                                : bf2f(((const unsigned short*)bsv)[g * HH + j]);
        psv[g] = ps[(size_t)(g * BB + b) * HH + j] + bias;
    }

    const float i_g = sigm(pi[0] + psv[0]);
    const float f_g = sigm(pi[1] + psv[1]);
    const float g_t = tanhf(pi[2] + psv[2]);
    const float o_g = sigm(pi[3] + psv[3]);
    const float hw  = sigm(pi[4] + psv[4]);

    const float c_old = cbuf[b * HH + j];
    float c_new = i_g * g_t + f_g * c_old;
    float ov = o_g * tanhf(c_new);
    ov = hw * ov + (1.0f - hw) * pi[5];

    if (t >= len) { ov = 0.0f; c_new = 0.0f; }

    cbuf[b * HH + j] = c_new;
    hnext[b * HH + j] = f2bf(ov);
    if (FP32) ((float*)outv)[(size_t)(b * TT + t) * HH + j] = ov;
    else      ((unsigned short*)outv)[(size_t)(b * TT + t) * HH + j] = f2bf(ov);
}

__global__ __launch_bounds__(512) void epi_kernel(const float* ps, const unsigned short* projc,
                                                  const void* bsv, const int* len32,
                                                  float* cbuf, unsigned short* hnext, void* outv,
                                                  const int* flags, int t, int tl, int Tc) {
    const int f = flags[0], i64 = flags[1];
    if (f) { if (i64) epi_core<1,1>(ps, projc, bsv, len32, cbuf, hnext, outv, t, tl, Tc);
             else     epi_core<1,0>(ps, projc, bsv, len32, cbuf, hnext, outv, t, tl, Tc); }
    else   { if (i64) epi_core<0,1>(ps, projc, bsv, len32, cbuf, hnext, outv, t, tl, Tc);
             else     epi_core<0,0>(ps, projc, bsv, len32, cbuf, hnext, outv, t, tl, Tc); }
}

// ---------------------------------------------------------------------------
extern "C" void kernel_launch(void* const* d_in, const int* in_sizes, int n_in,
                              void* d_out, int out_size, void* d_ws, size_t ws_size,
                              hipStream_t stream) {
    const void* xv      = d_in[0];
    const int*  len     = (const int*)d_in[1];
    const void* w_in    = d_in[2];
    const void* b_in    = d_in[3];
    const void* w_state = d_in[4];
    const void* b_state = d_in[5];

    char* ws = (char*)d_ws;
    int* flags = (int*)(ws + WS_FLAGS);
    unsigned short* hbuf = (unsigned short*)(ws + WS_H);
    float* cbuf = (float*)(ws + WS_C);
    float* ps   = (float*)(ws + WS_PS);
    unsigned short* projc = (unsigned short*)(ws + WS_PROJ);

    // Pick largest proj chunk (in timesteps, power of 2, >= 64) fitting ws.
    int tc_shift = 9;  // Tc = 512 (whole T)
    while (tc_shift > 6 &&
           WS_PROJ + ((size_t)BB << tc_shift) * SIXH * 2 > ws_size) tc_shift--;
    const int Tc = 1 << tc_shift;

    detect_kernel<<<1, 64, 0, stream>>>((const unsigned short*)xv, len, flags);
    hipMemsetAsync(ws + WS_H, 0, WS_PS - WS_H, stream);   // zero h ping-pong + c

    for (int c = 0; c < TT / Tc; c++) {
        const int t0 = c * Tc;
        proj_kernel<<<dim3(SIXH / 64, Tc), 256, 0, stream>>>(xv, w_in, b_in, projc, flags, t0, tc_shift);
        for (int tlocal = 0; tlocal < Tc; tlocal++) {
            const int t = t0 + tlocal;
            const unsigned short* hcur = hbuf + (t & 1) * (BB * HH);
            unsigned short* hnext      = hbuf + ((t + 1) & 1) * (BB * HH);
            ps_kernel<<<dim3(8, 5), 256, 0, stream>>>(hcur, w_state, ps, flags);
            epi_kernel<<<BB, HH, 0, stream>>>(ps, projc, b_state, len, cbuf, hnext, d_out,
                                              flags, t, tlocal, Tc);
        }
    }
}

// Round 3
// 8546.081 us; speedup vs baseline: 1.1486x; 1.1486x over previous
//
#include <hip/hip_runtime.h>
#include <cstdint>
#include <cstddef>

// Problem constants (AugmentedLstm: B=64, T=512, D=512, H=512)
#define BB 64
#define TT 512
#define DD 512
#define HH 512
#define SIXH 3072
#define NWG 32           // persistent recurrence workgroups (j-slices of 16)

typedef __attribute__((ext_vector_type(8))) short bf16x8;
typedef __attribute__((ext_vector_type(4))) float f32x4;

// ---- ws layout (byte offsets, 256-aligned) --------------------------------
#define WS_FLAGS 0u        // 2 ints: [0] fp32-inputs flag, [1] int64-lengths flag
#define WS_CNT   256u      // 512 ints: per-step arrival counters          (2048 B)
#define WS_H     2560u     // 2 x [BB][HH] ushort bf16 h ping-pong       (131072 B)
#define WS_C     133632u   // [BB][HH] float c                           (131072 B)
#define WS_PROJ  264960u   // proj chunk: [b][tl][6H] bf16, Tc*BB rows

__device__ __forceinline__ float bf2f(unsigned short u) {
    union { unsigned int i; float f; } v; v.i = ((unsigned int)u) << 16; return v.f;
}
__device__ __forceinline__ unsigned short f2bf(float f) {
    union { unsigned int i; float f; } v; v.f = f;
    unsigned int r = v.i + 0x7FFFu + ((v.i >> 16) & 1u);  // RNE
    return (unsigned short)(r >> 16);
}
__device__ __forceinline__ float sigm(float x) { return 1.0f / (1.0f + __expf(-x)); }
__device__ __forceinline__ float tanh_fast(float x) {
    // 1 - 2/(e^{2x}+1): exact limits at +-inf, NaN-free for finite x
    return 1.0f - 2.0f / (__expf(2.0f * x) + 1.0f);
}

__device__ __forceinline__ bf16x8 cvt8(const float* p) {
    bf16x8 o;
#pragma unroll
    for (int i = 0; i < 8; i++) o[i] = (short)f2bf(p[i]);
    return o;
}

// ---------------------------------------------------------------------------
// Detect input dtypes from raw bits (proven in round 2).
// ---------------------------------------------------------------------------
__global__ void detect_kernel(const unsigned short* __restrict__ x16,
                              const int* __restrict__ len32,
                              int* __restrict__ flags) {
    if (threadIdx.x == 0 && blockIdx.x == 0) {
        int bad = 0;
        for (int i = 0; i < 256; i++) {
            float a = fabsf(bf2f(x16[i]));
            if (a > 1e4f) bad++;
        }
        flags[0] = (bad >= 16) ? 1 : 0;
        flags[1] = (len32[1] == 0 && len32[3] == 0 && len32[5] == 0) ? 1 : 0;
    }
}

// ---------------------------------------------------------------------------
// Proj chunk GEMM (unchanged from round 2, proven correct):
// projc[(b*Tc + tl)*6H + n] = x[b][t0+tl][:] . w_in[n][:] + b_in[n]
// ---------------------------------------------------------------------------
template<int FP32>
__device__ __forceinline__ void proj_core(const void* __restrict__ xv,
                                          const void* __restrict__ wv,
                                          const void* __restrict__ bv,
                                          unsigned short* __restrict__ projc,
                                          int t0, int tc_shift) {
    const int tid  = threadIdx.x;
    const int wave = tid >> 6;
    const int lane = tid & 63;
    const int q    = lane >> 4;
    const int r    = lane & 15;

    const int m_blk = blockIdx.y * 64 + (wave >> 1) * 32;
    const int n_blk = blockIdx.x * 64 + (wave & 1) * 32;
    const int Tc    = 1 << tc_shift;
    const int b     = m_blk >> tc_shift;
    const int tl    = m_blk & (Tc - 1);

    const size_t xrow0 = (size_t)(b * TT + t0 + tl + r) * DD;
    const size_t xrow1 = (size_t)(b * TT + t0 + tl + 16 + r) * DD;
    const size_t wrow0 = (size_t)(n_blk + r) * DD;
    const size_t wrow1 = (size_t)(n_blk + 16 + r) * DD;

    f32x4 acc[2][2] = {};
    const int koff = q * 8;
    for (int k0 = 0; k0 < DD; k0 += 32) {
        bf16x8 a0, a1, b0, b1;
        const int k = k0 + koff;
        if (FP32) {
            const float* xf = (const float*)xv;
            const float* wf = (const float*)wv;
            a0 = cvt8(xf + xrow0 + k);  a1 = cvt8(xf + xrow1 + k);
            b0 = cvt8(wf + wrow0 + k);  b1 = cvt8(wf + wrow1 + k);
        } else {
            const unsigned short* xb = (const unsigned short*)xv;
            const unsigned short* wb = (const unsigned short*)wv;
            a0 = *(const bf16x8*)(xb + xrow0 + k);  a1 = *(const bf16x8*)(xb + xrow1 + k);
            b0 = *(const bf16x8*)(wb + wrow0 + k);  b1 = *(const bf16x8*)(wb + wrow1 + k);
        }
        acc[0][0] = __builtin_amdgcn_mfma_f32_16x16x32_bf16(a0, b0, acc[0][0], 0, 0, 0);
        acc[0][1] = __builtin_amdgcn_mfma_f32_16x16x32_bf16(a0, b1, acc[0][1], 0, 0, 0);
        acc[1][0] = __builtin_amdgcn_mfma_f32_16x16x32_bf16(a1, b0, acc[1][0], 0, 0, 0);
        acc[1][1] = __builtin_amdgcn_mfma_f32_16x16x32_bf16(a1, b1, acc[1][1], 0, 0, 0);
    }

#pragma unroll
    for (int mi = 0; mi < 2; mi++) {
#pragma unroll
        for (int ni = 0; ni < 2; ni++) {
            const int n = n_blk + ni * 16 + r;
            const float bias = FP32 ? ((const float*)bv)[n] : bf2f(((const unsigned short*)bv)[n]);
#pragma unroll
            for (int rr = 0; rr < 4; rr++) {
                const int m = m_blk + mi * 16 + q * 4 + rr;
                projc[(size_t)m * SIXH + n] = f2bf(acc[mi][ni][rr] + bias);
            }
        }
    }
}

__global__ __launch_bounds__(256) void proj_kernel(const void* xv, const void* wv, const void* bv,
                                                   unsigned short* projc, const int* flags,
                                                   int t0, int tc_shift) {
    if (flags[0]) proj_core<1>(xv, wv, bv, projc, t0, tc_shift);
    else          proj_core<0>(xv, wv, bv, projc, t0, tc_shift);
}

// ---------------------------------------------------------------------------
// Persistent recurrence kernel. Grid: NWG=32 blocks x 128 threads (2 waves).
// Block wg owns output columns j in [wg*16, wg*16+16).
//   - W_state rows {g*H + j0 + jj : g<5, jj<16} (80 rows x 512) live in LDS
//     for the whole kernel (83.2 KB with +8 bf16 row pad).
//   - Wave wv handles batches [wv*32, wv*32+32): per step a [32 x 80 x 512]
//     MFMA GEMM; D-layout gives each lane all 5 gates for its (b, j) pairs.
//   - c state stays in VGPRs across all steps (persisted to ws at kernel end
//     for chunked mode).
//   - Cross-wg per-step barrier: h bf16 ping-pong in ws; agent-scope
//     release-counter cnt[t] (+ agent fences) guards slot (t+1)&1.
// ---------------------------------------------------------------------------
__global__ __launch_bounds__(128) void rec_kernel(
    const unsigned short* __restrict__ projc,
    const void* __restrict__ wsv, const void* __restrict__ bsv,
    const int* __restrict__ len32,
    unsigned short* __restrict__ hbuf, float* __restrict__ cbuf,
    int* __restrict__ cnt, void* __restrict__ outv,
    const int* __restrict__ flags, int t0, int Tc)
{
    const int fp32 = flags[0], i64 = flags[1];
    const int tid  = threadIdx.x;
    const int wv   = tid >> 6;
    const int lane = tid & 63;
    const int q    = lane >> 4;
    const int r    = lane & 15;
    const int j0   = blockIdx.x * 16;

    __shared__ unsigned short wlds[80 * 520];   // rows padded 512 -> 520

    // --- stage W_state slice into LDS (once) ---
    if (fp32) {
        const float* w = (const float*)wsv;
        for (int v = tid; v < 80 * 64; v += 128) {
            const int row = v >> 6, c8 = (v & 63) * 8;
            const int grow = (row >> 4) * HH + j0 + (row & 15);
            *(bf16x8*)&wlds[row * 520 + c8] = cvt8(w + (size_t)grow * HH + c8);
        }
    } else {
        const unsigned short* w = (const unsigned short*)wsv;
        for (int v = tid; v < 80 * 64; v += 128) {
            const int row = v >> 6, c8 = (v & 63) * 8;
            const int grow = (row >> 4) * HH + j0 + (row & 15);
            *(bf16x8*)&wlds[row * 520 + c8] = *(const bf16x8*)(w + (size_t)grow * HH + c8);
        }
    }

    // --- per-lane persistent state ---
    float bs[5];
#pragma unroll
    for (int g = 0; g < 5; g++)
        bs[g] = fp32 ? ((const float*)bsv)[g * HH + j0 + r]
                     : bf2f(((const unsigned short*)bsv)[g * HH + j0 + r]);

    int   lens[8];
    float creg[8];
#pragma unroll
    for (int mi = 0; mi < 2; mi++)
#pragma unroll
        for (int rr = 0; rr < 4; rr++) {
            const int b = wv * 32 + mi * 16 + q * 4 + rr;
            lens[mi * 4 + rr] = i64 ? len32[2 * b] : len32[b];
            creg[mi * 4 + rr] = cbuf[b * HH + j0 + r];
        }

    __syncthreads();   // wlds ready

    for (int t = t0; t < t0 + Tc; t++) {
        const unsigned short* hcur = hbuf + (t & 1) * (BB * HH);
        unsigned short*       hnxt = hbuf + ((t + 1) & 1) * (BB * HH);

        if (t > t0) {   // wait for all h-slices of step t-1 (t==t0: stream order)
            if (tid == 0) {
                while (__hip_atomic_load(&cnt[t - 1], __ATOMIC_ACQUIRE,
                                         __HIP_MEMORY_SCOPE_AGENT) < NWG) {}
            }
            __syncthreads();
            __builtin_amdgcn_fence(__ATOMIC_ACQUIRE, "agent");
        }

        // --- GEMM: ps[b in wave-half][80 rows] ---
        f32x4 acc[2][5] = {};
        const unsigned short* h0 = hcur + (size_t)(wv * 32 + r) * HH + q * 8;
        const unsigned short* h1 = h0 + (size_t)16 * HH;
#pragma unroll 4
        for (int k0 = 0; k0 < HH; k0 += 32) {
            bf16x8 a0 = *(const bf16x8*)(h0 + k0);
            bf16x8 a1 = *(const bf16x8*)(h1 + k0);
#pragma unroll
            for (int g = 0; g < 5; g++) {
                bf16x8 bw = *(const bf16x8*)&wlds[(g * 16 + r) * 520 + k0 + q * 8];
                acc[0][g] = __builtin_amdgcn_mfma_f32_16x16x32_bf16(a0, bw, acc[0][g], 0, 0, 0);
                acc[1][g] = __builtin_amdgcn_mfma_f32_16x16x32_bf16(a1, bw, acc[1][g], 0, 0, 0);
            }
        }

        // --- register epilogue: lane owns (b = wv*32+mi*16+q*4+rr, j = j0+r) ---
        const int tl = t - t0;
#pragma unroll
        for (int mi = 0; mi < 2; mi++)
#pragma unroll
            for (int rr = 0; rr < 4; rr++) {
                const int b = wv * 32 + mi * 16 + q * 4 + rr;
                const unsigned short* pb = projc + ((size_t)b * Tc + tl) * SIXH + j0 + r;
                const float i_g = sigm(bf2f(pb[0 * HH]) + acc[mi][0][rr] + bs[0]);
                const float f_g = sigm(bf2f(pb[1 * HH]) + acc[mi][1][rr] + bs[1]);
                const float g_t = tanh_fast(bf2f(pb[2 * HH]) + acc[mi][2][rr] + bs[2]);
                const float o_g = sigm(bf2f(pb[3 * HH]) + acc[mi][3][rr] + bs[3]);
                const float hw  = sigm(bf2f(pb[4 * HH]) + acc[mi][4][rr] + bs[4]);

                const float c_old = creg[mi * 4 + rr];
                float c_new = i_g * g_t + f_g * c_old;
                float ov = o_g * tanh_fast(c_new);
                ov = hw * ov + (1.0f - hw) * bf2f(pb[5 * HH]);
                if (t >= lens[mi * 4 + rr]) { ov = 0.0f; c_new = 0.0f; }
                creg[mi * 4 + rr] = c_new;

                hnxt[(size_t)b * HH + j0 + r] = f2bf(ov);
                if (fp32) ((float*)outv)[((size_t)b * TT + t) * HH + j0 + r] = ov;
                else ((unsigned short*)outv)[((size_t)b * TT + t) * HH + j0 + r] = f2bf(ov);
            }

        // --- publish h for step t+1 ---
        __builtin_amdgcn_fence(__ATOMIC_RELEASE, "agent");
        __syncthreads();
        if (tid == 0)
            __hip_atomic_fetch_add(&cnt[t], 1, __ATOMIC_RELEASE, __HIP_MEMORY_SCOPE_AGENT);
    }

    // persist c for chunked mode
#pragma unroll
    for (int mi = 0; mi < 2; mi++)
#pragma unroll
        for (int rr = 0; rr < 4; rr++) {
            const int b = wv * 32 + mi * 16 + q * 4 + rr;
            cbuf[b * HH + j0 + r] = creg[mi * 4 + rr];
        }
}

// ---------------------------------------------------------------------------
extern "C" void kernel_launch(void* const* d_in, const int* in_sizes, int n_in,
                              void* d_out, int out_size, void* d_ws, size_t ws_size,
                              hipStream_t stream) {
    const void* xv      = d_in[0];
    const int*  len     = (const int*)d_in[1];
    const void* w_in    = d_in[2];
    const void* b_in    = d_in[3];
    const void* w_state = d_in[4];
    const void* b_state = d_in[5];

    char* ws = (char*)d_ws;
    int* flags = (int*)(ws + WS_FLAGS);
    int* cnt   = (int*)(ws + WS_CNT);
    unsigned short* hbuf = (unsigned short*)(ws + WS_H);
    float* cbuf = (float*)(ws + WS_C);
    unsigned short* projc = (unsigned short*)(ws + WS_PROJ);

    // Largest proj chunk (timesteps, power of 2, >= 64) fitting ws.
    int tc_shift = 9;
    while (tc_shift > 6 &&
           WS_PROJ + ((size_t)BB << tc_shift) * SIXH * 2 > ws_size) tc_shift--;
    const int Tc = 1 << tc_shift;

    detect_kernel<<<1, 64, 0, stream>>>((const unsigned short*)xv, len, flags);
    // zero cnt + h ping-pong + c
    hipMemsetAsync(ws + WS_CNT, 0, WS_PROJ - WS_CNT, stream);

    for (int c = 0; c < TT / Tc; c++) {
        const int t0 = c * Tc;
        proj_kernel<<<dim3(SIXH / 64, (BB << tc_shift) >> 6), 256, 0, stream>>>(
            xv, w_in, b_in, projc, flags, t0, tc_shift);
        rec_kernel<<<NWG, 128, 0, stream>>>(projc, w_state, b_state, len,
                                            hbuf, cbuf, cnt, d_out, flags, t0, Tc);
    }
}

// Round 4
// 6548.121 us; speedup vs baseline: 1.4990x; 1.3051x over previous
//
#include <hip/hip_runtime.h>
#include <cstdint>
#include <cstddef>

// Problem constants (AugmentedLstm: B=64, T=512, D=512, H=512)
#define BB 64
#define TT 512
#define DD 512
#define HH 512
#define SIXH 3072
#define NWG 32           // persistent recurrence workgroups (j-slices of 16)

typedef __attribute__((ext_vector_type(8))) short bf16x8;
typedef __attribute__((ext_vector_type(4))) float f32x4;
typedef __attribute__((ext_vector_type(4))) unsigned short u16x4;

// ---- ws layout (byte offsets, 256-aligned) --------------------------------
#define WS_FLAGS 0u        // 2 ints: [0] fp32-inputs flag, [1] int64-lengths flag
#define WS_CNT   256u      // 512 ints: per-step arrival counters          (2048 B)
#define WS_H     2560u     // 2 x [BB][HH] ushort bf16 h ping-pong       (131072 B)
#define WS_C     133632u   // [BB][HH] float c                           (131072 B)
#define WS_PROJ  264960u   // proj chunk: [b][tl][6H] bf16, Tc*BB rows

__device__ __forceinline__ float bf2f(unsigned short u) {
    union { unsigned int i; float f; } v; v.i = ((unsigned int)u) << 16; return v.f;
}
__device__ __forceinline__ unsigned short f2bf(float f) {
    union { unsigned int i; float f; } v; v.f = f;
    unsigned int r = v.i + 0x7FFFu + ((v.i >> 16) & 1u);  // RNE
    return (unsigned short)(r >> 16);
}
__device__ __forceinline__ float sigm(float x) { return 1.0f / (1.0f + __expf(-x)); }
__device__ __forceinline__ float tanh_fast(float x) {
    return 1.0f - 2.0f / (__expf(2.0f * x) + 1.0f);   // NaN-free, exact at +-inf
}

__device__ __forceinline__ bf16x8 cvt8(const float* p) {
    bf16x8 o;
#pragma unroll
    for (int i = 0; i < 8; i++) o[i] = (short)f2bf(p[i]);
    return o;
}

// ---------------------------------------------------------------------------
// Detect input dtypes from raw bits (proven in rounds 2-3).
// ---------------------------------------------------------------------------
__global__ void detect_kernel(const unsigned short* __restrict__ x16,
                              const int* __restrict__ len32,
                              int* __restrict__ flags) {
    if (threadIdx.x == 0 && blockIdx.x == 0) {
        int bad = 0;
        for (int i = 0; i < 256; i++) {
            float a = fabsf(bf2f(x16[i]));
            if (a > 1e4f) bad++;
        }
        flags[0] = (bad >= 16) ? 1 : 0;
        flags[1] = (len32[1] == 0 && len32[3] == 0 && len32[5] == 0) ? 1 : 0;
    }
}

// ---------------------------------------------------------------------------
// Proj chunk GEMM (unchanged from round 2, proven correct):
// projc[(b*Tc + tl)*6H + n] = x[b][t0+tl][:] . w_in[n][:] + b_in[n]
// ---------------------------------------------------------------------------
template<int FP32>
__device__ __forceinline__ void proj_core(const void* __restrict__ xv,
                                          const void* __restrict__ wv,
                                          const void* __restrict__ bv,
                                          unsigned short* __restrict__ projc,
                                          int t0, int tc_shift) {
    const int tid  = threadIdx.x;
    const int wave = tid >> 6;
    const int lane = tid & 63;
    const int q    = lane >> 4;
    const int r    = lane & 15;

    const int m_blk = blockIdx.y * 64 + (wave >> 1) * 32;
    const int n_blk = blockIdx.x * 64 + (wave & 1) * 32;
    const int Tc    = 1 << tc_shift;
    const int b     = m_blk >> tc_shift;
    const int tl    = m_blk & (Tc - 1);

    const size_t xrow0 = (size_t)(b * TT + t0 + tl + r) * DD;
    const size_t xrow1 = (size_t)(b * TT + t0 + tl + 16 + r) * DD;
    const size_t wrow0 = (size_t)(n_blk + r) * DD;
    const size_t wrow1 = (size_t)(n_blk + 16 + r) * DD;

    f32x4 acc[2][2] = {};
    const int koff = q * 8;
    for (int k0 = 0; k0 < DD; k0 += 32) {
        bf16x8 a0, a1, b0, b1;
        const int k = k0 + koff;
        if (FP32) {
            const float* xf = (const float*)xv;
            const float* wf = (const float*)wv;
            a0 = cvt8(xf + xrow0 + k);  a1 = cvt8(xf + xrow1 + k);
            b0 = cvt8(wf + wrow0 + k);  b1 = cvt8(wf + wrow1 + k);
        } else {
            const unsigned short* xb = (const unsigned short*)xv;
            const unsigned short* wb = (const unsigned short*)wv;
            a0 = *(const bf16x8*)(xb + xrow0 + k);  a1 = *(const bf16x8*)(xb + xrow1 + k);
            b0 = *(const bf16x8*)(wb + wrow0 + k);  b1 = *(const bf16x8*)(wb + wrow1 + k);
        }
        acc[0][0] = __builtin_amdgcn_mfma_f32_16x16x32_bf16(a0, b0, acc[0][0], 0, 0, 0);
        acc[0][1] = __builtin_amdgcn_mfma_f32_16x16x32_bf16(a0, b1, acc[0][1], 0, 0, 0);
        acc[1][0] = __builtin_amdgcn_mfma_f32_16x16x32_bf16(a1, b0, acc[1][0], 0, 0, 0);
        acc[1][1] = __builtin_amdgcn_mfma_f32_16x16x32_bf16(a1, b1, acc[1][1], 0, 0, 0);
    }

#pragma unroll
    for (int mi = 0; mi < 2; mi++) {
#pragma unroll
        for (int ni = 0; ni < 2; ni++) {
            const int n = n_blk + ni * 16 + r;
            const float bias = FP32 ? ((const float*)bv)[n] : bf2f(((const unsigned short*)bv)[n]);
#pragma unroll
            for (int rr = 0; rr < 4; rr++) {
                const int m = m_blk + mi * 16 + q * 4 + rr;
                projc[(size_t)m * SIXH + n] = f2bf(acc[mi][ni][rr] + bias);
            }
        }
    }
}

__global__ __launch_bounds__(256) void proj_kernel(const void* xv, const void* wv, const void* bv,
                                                   unsigned short* projc, const int* flags,
                                                   int t0, int tc_shift) {
    if (flags[0]) proj_core<1>(xv, wv, bv, projc, t0, tc_shift);
    else          proj_core<0>(xv, wv, bv, projc, t0, tc_shift);
}

// ---------------------------------------------------------------------------
// Persistent recurrence kernel, v2. Grid: NWG=32 x 128 threads (2 waves).
// Block owns j in [wg*16, wg*16+16). MFMA roles: A = W_state rows (LDS,
// frag-linear swizzle -> conflict-free ds_read_b128), B = h rows (global,
// relaxed agent-scope 8B atomic loads = sc0/sc1 L3-coherent, NO fences).
// D layout: lane(q,r) holds ps[gate][j0+q*4+rr][b = wv*32+nt*16+r] -> 4
// consecutive j per lane => 8B projc loads / out stores / h atomic stores.
// Cross-WG step handshake: h ping-pong + relaxed agent counter; ordering via
// the vmcnt(0) drain __syncthreads already performs. No agent fences => L2
// stays warm for projc.
// ---------------------------------------------------------------------------
__global__ __launch_bounds__(128) void rec_kernel(
    const unsigned short* __restrict__ projc,
    const void* __restrict__ wsv, const void* __restrict__ bsv,
    const int* __restrict__ len32,
    unsigned short* __restrict__ hbuf, float* __restrict__ cbuf,
    int* __restrict__ cnt, void* __restrict__ outv,
    const int* __restrict__ flags, int t0, int Tc)
{
    const int fp32 = flags[0], i64 = flags[1];
    const int tid  = threadIdx.x;
    const int wv   = tid >> 6;
    const int lane = tid & 63;
    const int q    = lane >> 4;
    const int r    = lane & 15;
    const int j0   = blockIdx.x * 16;

    // frag-linear W_state slice: [5 gates][16 k-iters][64 lanes][8 ushort] = 80 KB
    __shared__ unsigned short wlds[5 * 16 * 64 * 8];

    for (int v = tid; v < 5 * 16 * 64; v += 128) {
        const int g  = v >> 10;
        const int ki = (v >> 6) & 15;
        const int ln = v & 63;
        const size_t gaddr = (size_t)(g * HH + j0 + (ln & 15)) * HH + ki * 32 + (ln >> 4) * 8;
        bf16x8 w8;
        if (fp32) w8 = cvt8((const float*)wsv + gaddr);
        else      w8 = *(const bf16x8*)((const unsigned short*)wsv + gaddr);
        *(bf16x8*)&wlds[(size_t)v * 8] = w8;
    }

    // per-lane persistent state: lane owns (b = wv*32+nt*16+r) x (j = j0+q*4+jj)
    float bs[5][4];
#pragma unroll
    for (int g = 0; g < 5; g++)
#pragma unroll
        for (int jj = 0; jj < 4; jj++)
            bs[g][jj] = fp32 ? ((const float*)bsv)[g * HH + j0 + q * 4 + jj]
                             : bf2f(((const unsigned short*)bsv)[g * HH + j0 + q * 4 + jj]);

    int   lens[2];
    float creg[2][4];
#pragma unroll
    for (int nt = 0; nt < 2; nt++) {
        const int b = wv * 32 + nt * 16 + r;
        lens[nt] = i64 ? len32[2 * b] : len32[b];
#pragma unroll
        for (int jj = 0; jj < 4; jj++)
            creg[nt][jj] = cbuf[b * HH + j0 + q * 4 + jj];
    }

    __syncthreads();   // wlds ready

    union U8 { unsigned long long u[2]; bf16x8 v; };
    union P8 { unsigned short s[4]; unsigned long long u; };

    for (int t = t0; t < t0 + Tc; t++) {
        const unsigned short* hcur = hbuf + (size_t)(t & 1) * (BB * HH);
        unsigned short*       hnxt = hbuf + (size_t)((t + 1) & 1) * (BB * HH);

        if (t > t0) {   // wait for all h-slices of step t-1 (t==t0: stream order)
            if (tid == 0) {
                while (__hip_atomic_load(&cnt[t - 1], __ATOMIC_RELAXED,
                                         __HIP_MEMORY_SCOPE_AGENT) < NWG) { }
            }
            __syncthreads();
        }

        // --- GEMM: acc[g][nt][jj] = ps[g*H + j0+q*4+jj][b = wv*32+nt*16+r] ---
        f32x4 acc[5][2] = {};
        {
            unsigned short* hc = const_cast<unsigned short*>(hcur);
            const int hrow0 = (wv * 32 + r) * HH;
            const int hrow1 = (wv * 32 + 16 + r) * HH;
#pragma unroll 4
            for (int ki = 0; ki < 16; ki++) {
                const int kc = ki * 32 + q * 8;
                U8 hb0, hb1;
                unsigned long long* p0 = (unsigned long long*)(hc + hrow0 + kc);
                unsigned long long* p1 = (unsigned long long*)(hc + hrow1 + kc);
                hb0.u[0] = __hip_atomic_load(p0,     __ATOMIC_RELAXED, __HIP_MEMORY_SCOPE_AGENT);
                hb0.u[1] = __hip_atomic_load(p0 + 1, __ATOMIC_RELAXED, __HIP_MEMORY_SCOPE_AGENT);
                hb1.u[0] = __hip_atomic_load(p1,     __ATOMIC_RELAXED, __HIP_MEMORY_SCOPE_AGENT);
                hb1.u[1] = __hip_atomic_load(p1 + 1, __ATOMIC_RELAXED, __HIP_MEMORY_SCOPE_AGENT);
#pragma unroll
                for (int g = 0; g < 5; g++) {
                    bf16x8 aw = *(const bf16x8*)&wlds[((g * 16 + ki) * 64 + lane) * 8];
                    acc[g][0] = __builtin_amdgcn_mfma_f32_16x16x32_bf16(aw, hb0.v, acc[g][0], 0, 0, 0);
                    acc[g][1] = __builtin_amdgcn_mfma_f32_16x16x32_bf16(aw, hb1.v, acc[g][1], 0, 0, 0);
                }
            }
        }

        // --- epilogue: lane owns 2 batches x 4 consecutive j ---
        const int tl = t - t0;
#pragma unroll
        for (int nt = 0; nt < 2; nt++) {
            const int b   = wv * 32 + nt * 16 + r;
            const int len = lens[nt];
            const unsigned short* pb = projc + ((size_t)b * Tc + tl) * SIXH + j0 + q * 4;
            u16x4 pv[6];
#pragma unroll
            for (int g = 0; g < 6; g++) pv[g] = *(const u16x4*)(pb + g * HH);

            P8 hp;
            float ov4[4];
#pragma unroll
            for (int jj = 0; jj < 4; jj++) {
                const float i_g = sigm(bf2f(pv[0][jj]) + acc[0][nt][jj] + bs[0][jj]);
                const float f_g = sigm(bf2f(pv[1][jj]) + acc[1][nt][jj] + bs[1][jj]);
                const float g_t = tanh_fast(bf2f(pv[2][jj]) + acc[2][nt][jj] + bs[2][jj]);
                const float o_g = sigm(bf2f(pv[3][jj]) + acc[3][nt][jj] + bs[3][jj]);
                const float hw  = sigm(bf2f(pv[4][jj]) + acc[4][nt][jj] + bs[4][jj]);

                float c_new = i_g * g_t + f_g * creg[nt][jj];
                float ov = o_g * tanh_fast(c_new);
                ov = hw * ov + (1.0f - hw) * bf2f(pv[5][jj]);
                if (t >= len) { ov = 0.0f; c_new = 0.0f; }
                creg[nt][jj] = c_new;
                ov4[jj] = ov;
                hp.s[jj] = f2bf(ov);
            }

            // h for next step: L3-coherent 8B atomic store (no fence needed)
            __hip_atomic_store((unsigned long long*)(hnxt + b * HH + j0 + q * 4), hp.u,
                               __ATOMIC_RELAXED, __HIP_MEMORY_SCOPE_AGENT);
            // output: normal cached stores (flushed at kernel end)
            if (fp32) {
                float* op = (float*)outv + ((size_t)b * TT + t) * HH + j0 + q * 4;
                *(float4*)op = make_float4(ov4[0], ov4[1], ov4[2], ov4[3]);
            } else {
                unsigned short* op = (unsigned short*)outv + ((size_t)b * TT + t) * HH + j0 + q * 4;
                *(unsigned long long*)op = hp.u;
            }
        }

        // --- publish: vmcnt(0) drain (explicit + barrier), then counter ---
        asm volatile("s_waitcnt vmcnt(0)" ::: "memory");
        __syncthreads();
        if (tid == 0)
            __hip_atomic_fetch_add(&cnt[t], 1, __ATOMIC_RELAXED, __HIP_MEMORY_SCOPE_AGENT);
    }

    // persist c for chunked mode
#pragma unroll
    for (int nt = 0; nt < 2; nt++) {
        const int b = wv * 32 + nt * 16 + r;
#pragma unroll
        for (int jj = 0; jj < 4; jj++)
            cbuf[b * HH + j0 + q * 4 + jj] = creg[nt][jj];
    }
}

// ---------------------------------------------------------------------------
extern "C" void kernel_launch(void* const* d_in, const int* in_sizes, int n_in,
                              void* d_out, int out_size, void* d_ws, size_t ws_size,
                              hipStream_t stream) {
    const void* xv      = d_in[0];
    const int*  len     = (const int*)d_in[1];
    const void* w_in    = d_in[2];
    const void* b_in    = d_in[3];
    const void* w_state = d_in[4];
    const void* b_state = d_in[5];

    char* ws = (char*)d_ws;
    int* flags = (int*)(ws + WS_FLAGS);
    int* cnt   = (int*)(ws + WS_CNT);
    unsigned short* hbuf = (unsigned short*)(ws + WS_H);
    float* cbuf = (float*)(ws + WS_C);
    unsigned short* projc = (unsigned short*)(ws + WS_PROJ);

    // Largest proj chunk (timesteps, power of 2, >= 64) fitting ws.
    int tc_shift = 9;
    while (tc_shift > 6 &&
           WS_PROJ + ((size_t)BB << tc_shift) * SIXH * 2 > ws_size) tc_shift--;
    const int Tc = 1 << tc_shift;

    detect_kernel<<<1, 64, 0, stream>>>((const unsigned short*)xv, len, flags);
    // zero cnt + h ping-pong + c
    hipMemsetAsync(ws + WS_CNT, 0, WS_PROJ - WS_CNT, stream);

    for (int c = 0; c < TT / Tc; c++) {
        const int t0 = c * Tc;
        proj_kernel<<<dim3(SIXH / 64, (BB << tc_shift) >> 6), 256, 0, stream>>>(
            xv, w_in, b_in, projc, flags, t0, tc_shift);
        rec_kernel<<<NWG, 128, 0, stream>>>(projc, w_state, b_state, len,
                                            hbuf, cbuf, cnt, d_out, flags, t0, Tc);
    }
}

// Round 5
// 5620.185 us; speedup vs baseline: 1.7465x; 1.1651x over previous
//
#include <hip/hip_runtime.h>
#include <cstdint>
#include <cstddef>

// Problem constants (AugmentedLstm: B=64, T=512, D=512, H=512)
#define BB 64
#define TT 512
#define DD 512
#define HH 512
#define SIXH 3072
#define NWG 32           // persistent recurrence workgroups (j-slices of 16)

typedef __attribute__((ext_vector_type(8))) short bf16x8;
typedef __attribute__((ext_vector_type(4))) float f32x4;
typedef __attribute__((ext_vector_type(4))) unsigned short u16x4;
typedef __attribute__((ext_vector_type(4))) int i32x4;

// ---- ws layout (byte offsets) ---------------------------------------------
#define WS_FLAGS 0u        // 2 ints: [0] fp32-inputs flag, [1] int64-lengths flag
#define WS_CNT   256u      // 32 per-WG step flags, stride 32 ints (128 B each) = 4096 B
#define WS_H     4352u     // 2 x [BB][HH] ushort bf16 h ping-pong (131072 B)
#define WS_C     135424u   // [BB][HH] float c (131072 B)
#define WS_PROJ  266496u   // proj chunk: [b][tl][6H] bf16, Tc*BB rows

// Coherent (L2-bypassing, L3-visible) 16B load / 8B store via explicit sc0 sc1.
#define CLOAD16(dst, ptr) \
    asm volatile("global_load_dwordx4 %0, %1, off sc0 sc1" : "=v"(dst) : "v"(ptr))
#define CSTORE8(ptr, val) \
    asm volatile("global_store_dwordx2 %0, %1, off sc0 sc1" :: "v"(ptr), "v"(val))
// waitcnt tied to the 8 regs of one ki-chunk so MFMAs can't be hoisted above it
#define WAIT8(N, a,b,c,d,e,f,g,h) \
    asm volatile("s_waitcnt vmcnt(" N ")" \
                 : "+v"(a),"+v"(b),"+v"(c),"+v"(d),"+v"(e),"+v"(f),"+v"(g),"+v"(h))

__device__ __forceinline__ float bf2f(unsigned short u) {
    union { unsigned int i; float f; } v; v.i = ((unsigned int)u) << 16; return v.f;
}
__device__ __forceinline__ unsigned short f2bf(float f) {
    union { unsigned int i; float f; } v; v.f = f;
    unsigned int r = v.i + 0x7FFFu + ((v.i >> 16) & 1u);  // RNE
    return (unsigned short)(r >> 16);
}
__device__ __forceinline__ float sigm(float x) { return 1.0f / (1.0f + __expf(-x)); }
__device__ __forceinline__ float tanh_fast(float x) {
    return 1.0f - 2.0f / (__expf(2.0f * x) + 1.0f);   // NaN-free, exact at +-inf
}

__device__ __forceinline__ bf16x8 cvt8(const float* p) {
    bf16x8 o;
#pragma unroll
    for (int i = 0; i < 8; i++) o[i] = (short)f2bf(p[i]);
    return o;
}

// ---------------------------------------------------------------------------
// Detect input dtypes from raw bits (parallelized; logic proven rounds 2-4).
// ---------------------------------------------------------------------------
__global__ void detect_kernel(const unsigned short* __restrict__ x16,
                              const int* __restrict__ len32,
                              int* __restrict__ flags) {
    const int lane = threadIdx.x;   // 64
    int bad = 0;
    for (int i = lane; i < 256; i += 64)
        if (fabsf(bf2f(x16[i])) > 1e4f) bad++;
#pragma unroll
    for (int off = 32; off; off >>= 1) bad += __shfl_down(bad, off);
    if (lane == 0) {
        flags[0] = (bad >= 16) ? 1 : 0;
        flags[1] = (len32[1] == 0 && len32[3] == 0 && len32[5] == 0) ? 1 : 0;
    }
}

// ---------------------------------------------------------------------------
// Proj chunk GEMM (unchanged from rounds 2-4, proven correct):
// projc[(b*Tc + tl)*6H + n] = x[b][t0+tl][:] . w_in[n][:] + b_in[n]
// ---------------------------------------------------------------------------
template<int FP32>
__device__ __forceinline__ void proj_core(const void* __restrict__ xv,
                                          const void* __restrict__ wv,
                                          const void* __restrict__ bv,
                                          unsigned short* __restrict__ projc,
                                          int t0, int tc_shift) {
    const int tid  = threadIdx.x;
    const int wave = tid >> 6;
    const int lane = tid & 63;
    const int q    = lane >> 4;
    const int r    = lane & 15;

    const int m_blk = blockIdx.y * 64 + (wave >> 1) * 32;
    const int n_blk = blockIdx.x * 64 + (wave & 1) * 32;
    const int Tc    = 1 << tc_shift;
    const int b     = m_blk >> tc_shift;
    const int tl    = m_blk & (Tc - 1);

    const size_t xrow0 = (size_t)(b * TT + t0 + tl + r) * DD;
    const size_t xrow1 = (size_t)(b * TT + t0 + tl + 16 + r) * DD;
    const size_t wrow0 = (size_t)(n_blk + r) * DD;
    const size_t wrow1 = (size_t)(n_blk + 16 + r) * DD;

    f32x4 acc[2][2] = {};
    const int koff = q * 8;
    for (int k0 = 0; k0 < DD; k0 += 32) {
        bf16x8 a0, a1, b0, b1;
        const int k = k0 + koff;
        if (FP32) {
            const float* xf = (const float*)xv;
            const float* wf = (const float*)wv;
            a0 = cvt8(xf + xrow0 + k);  a1 = cvt8(xf + xrow1 + k);
            b0 = cvt8(wf + wrow0 + k);  b1 = cvt8(wf + wrow1 + k);
        } else {
            const unsigned short* xb = (const unsigned short*)xv;
            const unsigned short* wb = (const unsigned short*)wv;
            a0 = *(const bf16x8*)(xb + xrow0 + k);  a1 = *(const bf16x8*)(xb + xrow1 + k);
            b0 = *(const bf16x8*)(wb + wrow0 + k);  b1 = *(const bf16x8*)(wb + wrow1 + k);
        }
        acc[0][0] = __builtin_amdgcn_mfma_f32_16x16x32_bf16(a0, b0, acc[0][0], 0, 0, 0);
        acc[0][1] = __builtin_amdgcn_mfma_f32_16x16x32_bf16(a0, b1, acc[0][1], 0, 0, 0);
        acc[1][0] = __builtin_amdgcn_mfma_f32_16x16x32_bf16(a1, b0, acc[1][0], 0, 0, 0);
        acc[1][1] = __builtin_amdgcn_mfma_f32_16x16x32_bf16(a1, b1, acc[1][1], 0, 0, 0);
    }

#pragma unroll
    for (int mi = 0; mi < 2; mi++) {
#pragma unroll
        for (int ni = 0; ni < 2; ni++) {
            const int n = n_blk + ni * 16 + r;
            const float bias = FP32 ? ((const float*)bv)[n] : bf2f(((const unsigned short*)bv)[n]);
#pragma unroll
            for (int rr = 0; rr < 4; rr++) {
                const int m = m_blk + mi * 16 + q * 4 + rr;
                projc[(size_t)m * SIXH + n] = f2bf(acc[mi][ni][rr] + bias);
            }
        }
    }
}

__global__ __launch_bounds__(256) void proj_kernel(const void* xv, const void* wv, const void* bv,
                                                   unsigned short* projc, const int* flags,
                                                   int t0, int tc_shift) {
    if (flags[0]) proj_core<1>(xv, wv, bv, projc, t0, tc_shift);
    else          proj_core<0>(xv, wv, bv, projc, t0, tc_shift);
}

// ---------------------------------------------------------------------------
// Persistent recurrence kernel v3. Grid: NWG=32 x 128 threads (2 waves).
// vs v2: (a) h loaded via 32 up-front inline-asm coherent 16B loads per lane,
// consumed in 4 chunks gated by register-tied vmcnt(24/16/8/0) -> ONE L3
// latency instead of 16; (b) per-WG monotonic flag (own cacheline, plain
// atomic store) replaces the 32-way same-address RMW; consumers poll all 32
// flags in parallel (lane i reads flag i, __all).
// ---------------------------------------------------------------------------
__global__ __launch_bounds__(128, 1) void rec_kernel(
    const unsigned short* __restrict__ projc,
    const void* __restrict__ wsv, const void* __restrict__ bsv,
    const int* __restrict__ len32,
    unsigned short* __restrict__ hbuf, float* __restrict__ cbuf,
    int* __restrict__ wgflag, void* __restrict__ outv,
    const int* __restrict__ flags, int t0, int Tc)
{
    const int fp32 = flags[0], i64 = flags[1];
    const int tid  = threadIdx.x;
    const int wv   = tid >> 6;
    const int lane = tid & 63;
    const int q    = lane >> 4;
    const int r    = lane & 15;
    const int j0   = blockIdx.x * 16;

    // frag-linear W_state slice: [5 gates][16 ki][64 lanes][8 ushort] = 80 KB
    __shared__ unsigned short wlds[5 * 16 * 64 * 8];

    for (int v = tid; v < 5 * 16 * 64; v += 128) {
        const int g  = v >> 10;
        const int ki = (v >> 6) & 15;
        const int ln = v & 63;
        const size_t gaddr = (size_t)(g * HH + j0 + (ln & 15)) * HH + ki * 32 + (ln >> 4) * 8;
        bf16x8 w8;
        if (fp32) w8 = cvt8((const float*)wsv + gaddr);
        else      w8 = *(const bf16x8*)((const unsigned short*)wsv + gaddr);
        *(bf16x8*)&wlds[(size_t)v * 8] = w8;
    }

    // per-lane persistent state: lane owns (b = wv*32+nt*16+r) x (j = j0+q*4+jj)
    float bs[5][4];
#pragma unroll
    for (int g = 0; g < 5; g++)
#pragma unroll
        for (int jj = 0; jj < 4; jj++)
            bs[g][jj] = fp32 ? ((const float*)bsv)[g * HH + j0 + q * 4 + jj]
                             : bf2f(((const unsigned short*)bsv)[g * HH + j0 + q * 4 + jj]);

    int   lens[2];
    float creg[2][4];
#pragma unroll
    for (int nt = 0; nt < 2; nt++) {
        const int b = wv * 32 + nt * 16 + r;
        lens[nt] = i64 ? len32[2 * b] : len32[b];
#pragma unroll
        for (int jj = 0; jj < 4; jj++)
            creg[nt][jj] = cbuf[b * HH + j0 + q * 4 + jj];
    }

    __syncthreads();   // wlds ready

    union HU { i32x4 i; bf16x8 b; };
    union P8 { unsigned short s[4]; unsigned long long u; };

    for (int t = t0; t < t0 + Tc; t++) {
        const unsigned short* hcur = hbuf + (size_t)(t & 1) * (BB * HH);
        unsigned short*       hnxt = hbuf + (size_t)((t + 1) & 1) * (BB * HH);

        if (t > t0) {   // wait until all WGs published step t-1 (flag >= t)
            if (wv == 0) {
                bool done;
                do {
                    int f = (lane < NWG)
                        ? __hip_atomic_load(&wgflag[lane * 32], __ATOMIC_RELAXED,
                                            __HIP_MEMORY_SCOPE_AGENT)
                        : t;
                    done = __all(f >= t);
                    if (!done) __builtin_amdgcn_s_sleep(1);
                } while (!done);
            }
            __syncthreads();
            asm volatile("" ::: "memory");
        }

        // --- preload projc gate inputs (L2-cached; hides under GEMM) ---
        const int tl = t - t0;
        u16x4 pv[2][6];
#pragma unroll
        for (int nt = 0; nt < 2; nt++) {
            const unsigned short* pb =
                projc + ((size_t)(wv * 32 + nt * 16 + r) * Tc + tl) * SIXH + j0 + q * 4;
#pragma unroll
            for (int g = 0; g < 6; g++) pv[nt][g] = *(const u16x4*)(pb + g * HH);
        }

        // --- issue ALL 32 coherent h loads up-front (ki-major order) ---
        i32x4 hv[16][2];
#pragma unroll
        for (int ki = 0; ki < 16; ki++) {
#pragma unroll
            for (int nt = 0; nt < 2; nt++) {
                const unsigned short* hp =
                    hcur + (size_t)(wv * 32 + nt * 16 + r) * HH + ki * 32 + q * 8;
                CLOAD16(hv[ki][nt], hp);
            }
        }

        // --- GEMM in 4 chunks, each gated by a register-tied partial wait ---
        f32x4 acc[5][2] = {};
#define MFMA_CHUNK(KLO)                                                          \
        _Pragma("unroll")                                                        \
        for (int ki = (KLO); ki < (KLO) + 4; ki++) {                             \
            _Pragma("unroll")                                                    \
            for (int g = 0; g < 5; g++) {                                        \
                bf16x8 aw = *(const bf16x8*)&wlds[((g * 16 + ki) * 64 + lane) * 8]; \
                HU u0; u0.i = hv[ki][0];                                         \
                HU u1; u1.i = hv[ki][1];                                         \
                acc[g][0] = __builtin_amdgcn_mfma_f32_16x16x32_bf16(aw, u0.b, acc[g][0], 0, 0, 0); \
                acc[g][1] = __builtin_amdgcn_mfma_f32_16x16x32_bf16(aw, u1.b, acc[g][1], 0, 0, 0); \
            }                                                                    \
        }

        WAIT8("24", hv[0][0], hv[0][1], hv[1][0], hv[1][1],
                    hv[2][0], hv[2][1], hv[3][0], hv[3][1]);
        MFMA_CHUNK(0)
        WAIT8("16", hv[4][0], hv[4][1], hv[5][0], hv[5][1],
                    hv[6][0], hv[6][1], hv[7][0], hv[7][1]);
        MFMA_CHUNK(4)
        WAIT8("8",  hv[8][0], hv[8][1], hv[9][0], hv[9][1],
                    hv[10][0], hv[10][1], hv[11][0], hv[11][1]);
        MFMA_CHUNK(8)
        WAIT8("0",  hv[12][0], hv[12][1], hv[13][0], hv[13][1],
                    hv[14][0], hv[14][1], hv[15][0], hv[15][1]);
        MFMA_CHUNK(12)
#undef MFMA_CHUNK

        // --- epilogue: lane owns 2 batches x 4 consecutive j ---
#pragma unroll
        for (int nt = 0; nt < 2; nt++) {
            const int b   = wv * 32 + nt * 16 + r;
            const int len = lens[nt];
            P8 hp;
            float ov4[4];
#pragma unroll
            for (int jj = 0; jj < 4; jj++) {
                const float i_g = sigm(bf2f(pv[nt][0][jj]) + acc[0][nt][jj] + bs[0][jj]);
                const float f_g = sigm(bf2f(pv[nt][1][jj]) + acc[1][nt][jj] + bs[1][jj]);
                const float g_t = tanh_fast(bf2f(pv[nt][2][jj]) + acc[2][nt][jj] + bs[2][jj]);
                const float o_g = sigm(bf2f(pv[nt][3][jj]) + acc[3][nt][jj] + bs[3][jj]);
                const float hw  = sigm(bf2f(pv[nt][4][jj]) + acc[4][nt][jj] + bs[4][jj]);

                float c_new = i_g * g_t + f_g * creg[nt][jj];
                float ov = o_g * tanh_fast(c_new);
                ov = hw * ov + (1.0f - hw) * bf2f(pv[nt][5][jj]);
                if (t >= len) { ov = 0.0f; c_new = 0.0f; }
                creg[nt][jj] = c_new;
                ov4[jj] = ov;
                hp.s[jj] = f2bf(ov);
            }

            // h for next step: coherent 8B store
            CSTORE8((void*)(hnxt + (size_t)b * HH + j0 + q * 4), hp.u);
            // output: normal cached stores (flushed at kernel end)
            if (fp32) {
                float* op = (float*)outv + ((size_t)b * TT + t) * HH + j0 + q * 4;
                *(float4*)op = make_float4(ov4[0], ov4[1], ov4[2], ov4[3]);
            } else {
                unsigned short* op = (unsigned short*)outv + ((size_t)b * TT + t) * HH + j0 + q * 4;
                *(unsigned long long*)op = hp.u;
            }
        }

        // --- publish: drain stores, then per-WG monotonic flag ---
        asm volatile("s_waitcnt vmcnt(0)" ::: "memory");
        __syncthreads();
        if (tid == 0)
            __hip_atomic_store(&wgflag[blockIdx.x * 32], t + 1,
                               __ATOMIC_RELAXED, __HIP_MEMORY_SCOPE_AGENT);
    }

    // persist c for chunked mode
#pragma unroll
    for (int nt = 0; nt < 2; nt++) {
        const int b = wv * 32 + nt * 16 + r;
#pragma unroll
        for (int jj = 0; jj < 4; jj++)
            cbuf[b * HH + j0 + q * 4 + jj] = creg[nt][jj];
    }
}

// ---------------------------------------------------------------------------
extern "C" void kernel_launch(void* const* d_in, const int* in_sizes, int n_in,
                              void* d_out, int out_size, void* d_ws, size_t ws_size,
                              hipStream_t stream) {
    const void* xv      = d_in[0];
    const int*  len     = (const int*)d_in[1];
    const void* w_in    = d_in[2];
    const void* b_in    = d_in[3];
    const void* w_state = d_in[4];
    const void* b_state = d_in[5];

    char* ws = (char*)d_ws;
    int* flags  = (int*)(ws + WS_FLAGS);
    int* wgflag = (int*)(ws + WS_CNT);
    unsigned short* hbuf = (unsigned short*)(ws + WS_H);
    float* cbuf = (float*)(ws + WS_C);
    unsigned short* projc = (unsigned short*)(ws + WS_PROJ);

    // Largest proj chunk (timesteps, power of 2, >= 64) fitting ws.
    int tc_shift = 9;
    while (tc_shift > 6 &&
           WS_PROJ + ((size_t)BB << tc_shift) * SIXH * 2 > ws_size) tc_shift--;
    const int Tc = 1 << tc_shift;

    detect_kernel<<<1, 64, 0, stream>>>((const unsigned short*)xv, len, flags);
    // zero wg flags + h ping-pong + c
    hipMemsetAsync(ws + WS_CNT, 0, WS_PROJ - WS_CNT, stream);

    for (int c = 0; c < TT / Tc; c++) {
        const int t0 = c * Tc;
        proj_kernel<<<dim3(SIXH / 64, (BB << tc_shift) >> 6), 256, 0, stream>>>(
            xv, w_in, b_in, projc, flags, t0, tc_shift);
        rec_kernel<<<NWG, 128, 0, stream>>>(projc, w_state, b_state, len,
                                            hbuf, cbuf, wgflag, d_out, flags, t0, Tc);
    }
}

// Round 6
// 4049.223 us; speedup vs baseline: 2.4241x; 1.3880x over previous
//
#include <hip/hip_runtime.h>
#include <cstdint>
#include <cstddef>

// Problem constants (AugmentedLstm: B=64, T=512, D=512, H=512)
#define BB 64
#define TT 512
#define DD 512
#define HH 512
#define SIXH 3072
#define NWG 32           // persistent recurrence workgroups (j-slices of 16)

typedef __attribute__((ext_vector_type(8))) short bf16x8;
typedef __attribute__((ext_vector_type(4))) float f32x4;
typedef __attribute__((ext_vector_type(4))) unsigned short u16x4;
typedef __attribute__((ext_vector_type(4))) int i32x4;

// ---- ws layout (byte offsets) ---------------------------------------------
#define WS_FLAGS 0u        // 2 ints: [0] fp32-inputs flag, [1] int64-lengths flag
#define WS_CNT   256u      // 32 per-WG step flags, stride 32 ints (128 B each) = 4096 B
#define WS_H     4352u     // 2 x [BB][HH] ushort bf16 h ping-pong (131072 B)
#define WS_C     135424u   // [BB][HH] float c (131072 B)
#define WS_PROJ  266496u   // proj chunk: [b][tl][6H] bf16, Tc*BB rows

// Coherent (L2-bypassing, L3-visible) 16B load / 8B store via explicit sc0 sc1.
#define CLOAD16(dst, ptr) \
    asm volatile("global_load_dwordx4 %0, %1, off sc0 sc1" : "=v"(dst) : "v"(ptr))
#define CSTORE8(ptr, val) \
    asm volatile("global_store_dwordx2 %0, %1, off sc0 sc1" :: "v"(ptr), "v"(val))
// waitcnt tied to the 4 regs of one ki-chunk so MFMAs can't be hoisted above it
#define WAIT4(N, a,b,c,d) \
    asm volatile("s_waitcnt vmcnt(" N ")" : "+v"(a),"+v"(b),"+v"(c),"+v"(d))

__device__ __forceinline__ float bf2f(unsigned short u) {
    union { unsigned int i; float f; } v; v.i = ((unsigned int)u) << 16; return v.f;
}
__device__ __forceinline__ unsigned short f2bf(float f) {
    union { unsigned int i; float f; } v; v.f = f;
    unsigned int r = v.i + 0x7FFFu + ((v.i >> 16) & 1u);  // RNE
    return (unsigned short)(r >> 16);
}
__device__ __forceinline__ float sigm(float x) { return 1.0f / (1.0f + __expf(-x)); }
__device__ __forceinline__ float tanh_fast(float x) {
    return 1.0f - 2.0f / (__expf(2.0f * x) + 1.0f);   // NaN-free, exact at +-inf
}

__device__ __forceinline__ bf16x8 cvt8(const float* p) {
    bf16x8 o;
#pragma unroll
    for (int i = 0; i < 8; i++) o[i] = (short)f2bf(p[i]);
    return o;
}

// ---------------------------------------------------------------------------
// Detect input dtypes from raw bits (logic proven rounds 2-5).
// ---------------------------------------------------------------------------
__global__ void detect_kernel(const unsigned short* __restrict__ x16,
                              const int* __restrict__ len32,
                              int* __restrict__ flags) {
    const int lane = threadIdx.x;   // 64
    int bad = 0;
    for (int i = lane; i < 256; i += 64)
        if (fabsf(bf2f(x16[i])) > 1e4f) bad++;
#pragma unroll
    for (int off = 32; off; off >>= 1) bad += __shfl_down(bad, off);
    if (lane == 0) {
        flags[0] = (bad >= 16) ? 1 : 0;
        flags[1] = (len32[1] == 0 && len32[3] == 0 && len32[5] == 0) ? 1 : 0;
    }
}

// ---------------------------------------------------------------------------
// Proj chunk GEMM (unchanged, proven):
// projc[(b*Tc + tl)*6H + n] = x[b][t0+tl][:] . w_in[n][:] + b_in[n]
// ---------------------------------------------------------------------------
template<int FP32>
__device__ __forceinline__ void proj_core(const void* __restrict__ xv,
                                          const void* __restrict__ wv,
                                          const void* __restrict__ bv,
                                          unsigned short* __restrict__ projc,
                                          int t0, int tc_shift) {
    const int tid  = threadIdx.x;
    const int wave = tid >> 6;
    const int lane = tid & 63;
    const int q    = lane >> 4;
    const int r    = lane & 15;

    const int m_blk = blockIdx.y * 64 + (wave >> 1) * 32;
    const int n_blk = blockIdx.x * 64 + (wave & 1) * 32;
    const int Tc    = 1 << tc_shift;
    const int b     = m_blk >> tc_shift;
    const int tl    = m_blk & (Tc - 1);

    const size_t xrow0 = (size_t)(b * TT + t0 + tl + r) * DD;
    const size_t xrow1 = (size_t)(b * TT + t0 + tl + 16 + r) * DD;
    const size_t wrow0 = (size_t)(n_blk + r) * DD;
    const size_t wrow1 = (size_t)(n_blk + 16 + r) * DD;

    f32x4 acc[2][2] = {};
    const int koff = q * 8;
    for (int k0 = 0; k0 < DD; k0 += 32) {
        bf16x8 a0, a1, b0, b1;
        const int k = k0 + koff;
        if (FP32) {
            const float* xf = (const float*)xv;
            const float* wf = (const float*)wv;
            a0 = cvt8(xf + xrow0 + k);  a1 = cvt8(xf + xrow1 + k);
            b0 = cvt8(wf + wrow0 + k);  b1 = cvt8(wf + wrow1 + k);
        } else {
            const unsigned short* xb = (const unsigned short*)xv;
            const unsigned short* wb = (const unsigned short*)wv;
            a0 = *(const bf16x8*)(xb + xrow0 + k);  a1 = *(const bf16x8*)(xb + xrow1 + k);
            b0 = *(const bf16x8*)(wb + wrow0 + k);  b1 = *(const bf16x8*)(wb + wrow1 + k);
        }
        acc[0][0] = __builtin_amdgcn_mfma_f32_16x16x32_bf16(a0, b0, acc[0][0], 0, 0, 0);
        acc[0][1] = __builtin_amdgcn_mfma_f32_16x16x32_bf16(a0, b1, acc[0][1], 0, 0, 0);
        acc[1][0] = __builtin_amdgcn_mfma_f32_16x16x32_bf16(a1, b0, acc[1][0], 0, 0, 0);
        acc[1][1] = __builtin_amdgcn_mfma_f32_16x16x32_bf16(a1, b1, acc[1][1], 0, 0, 0);
    }

#pragma unroll
    for (int mi = 0; mi < 2; mi++) {
#pragma unroll
        for (int ni = 0; ni < 2; ni++) {
            const int n = n_blk + ni * 16 + r;
            const float bias = FP32 ? ((const float*)bv)[n] : bf2f(((const unsigned short*)bv)[n]);
#pragma unroll
            for (int rr = 0; rr < 4; rr++) {
                const int m = m_blk + mi * 16 + q * 4 + rr;
                projc[(size_t)m * SIXH + n] = f2bf(acc[mi][ni][rr] + bias);
            }
        }
    }
}

__global__ __launch_bounds__(256) void proj_kernel(const void* xv, const void* wv, const void* bv,
                                                   unsigned short* projc, const int* flags,
                                                   int t0, int tc_shift) {
    if (flags[0]) proj_core<1>(xv, wv, bv, projc, t0, tc_shift);
    else          proj_core<0>(xv, wv, bv, projc, t0, tc_shift);
}

// ---------------------------------------------------------------------------
// Persistent recurrence kernel v4. Grid: NWG=32 x 256 threads (4 waves).
// Wave w owns batches [w*16, w*16+16); block owns j in [wg*16, wg*16+16).
// vs v3: (a) projc gate inputs prefetched one step ahead (issued right after
// the flag publish -> HBM latency hides under the handshake); (b) out-stores
// moved AFTER the flag publish so vmcnt(0) drains only the 8B sc0 h-stores;
// (c) 4 waves halve per-wave GEMM (80 MFMA) + epilogue; (d) hot-spin poll.
// ---------------------------------------------------------------------------
__global__ __launch_bounds__(256, 1) void rec_kernel(
    const unsigned short* __restrict__ projc,
    const void* __restrict__ wsv, const void* __restrict__ bsv,
    const int* __restrict__ len32,
    unsigned short* __restrict__ hbuf, float* __restrict__ cbuf,
    int* __restrict__ wgflag, void* __restrict__ outv,
    const int* __restrict__ flags, int t0, int Tc)
{
    const int fp32 = flags[0], i64 = flags[1];
    const int tid  = threadIdx.x;
    const int wv   = tid >> 6;    // wave = batch group (0..3)
    const int lane = tid & 63;
    const int q    = lane >> 4;
    const int r    = lane & 15;
    const int j0   = blockIdx.x * 16;
    const int b    = wv * 16 + r;              // this lane's batch

    // frag-linear W_state slice: [5 gates][16 ki][64 lanes][8 ushort] = 80 KB
    __shared__ unsigned short wlds[5 * 16 * 64 * 8];

    for (int v = tid; v < 5 * 16 * 64; v += 256) {
        const int g  = v >> 10;
        const int ki = (v >> 6) & 15;
        const int ln = v & 63;
        const size_t gaddr = (size_t)(g * HH + j0 + (ln & 15)) * HH + ki * 32 + (ln >> 4) * 8;
        bf16x8 w8;
        if (fp32) w8 = cvt8((const float*)wsv + gaddr);
        else      w8 = *(const bf16x8*)((const unsigned short*)wsv + gaddr);
        *(bf16x8*)&wlds[(size_t)v * 8] = w8;
    }

    // per-lane persistent state: lane owns batch b x (j = j0+q*4+jj)
    float bs[5][4];
#pragma unroll
    for (int g = 0; g < 5; g++)
#pragma unroll
        for (int jj = 0; jj < 4; jj++)
            bs[g][jj] = fp32 ? ((const float*)bsv)[g * HH + j0 + q * 4 + jj]
                             : bf2f(((const unsigned short*)bsv)[g * HH + j0 + q * 4 + jj]);

    const int len = i64 ? len32[2 * b] : len32[b];
    float creg[4];
#pragma unroll
    for (int jj = 0; jj < 4; jj++)
        creg[jj] = cbuf[b * HH + j0 + q * 4 + jj];

    // initial projc gate inputs for tl = 0 (overlaps the wlds staging above)
    u16x4 pv[6];
    {
        const unsigned short* pb = projc + (size_t)b * Tc * SIXH + j0 + q * 4;
#pragma unroll
        for (int g = 0; g < 6; g++) pv[g] = *(const u16x4*)(pb + g * HH);
    }

    __syncthreads();   // wlds ready

    union HU { i32x4 i; bf16x8 b; };
    union P8 { unsigned short s[4]; unsigned long long u; };

    for (int t = t0; t < t0 + Tc; t++) {
        const unsigned short* hcur = hbuf + (size_t)(t & 1) * (BB * HH);
        unsigned short*       hnxt = hbuf + (size_t)((t + 1) & 1) * (BB * HH);

        if (t > t0) {   // wait until all WGs published step t-1 (flag >= t)
            if (wv == 0) {
                bool done;
                do {
                    int f = (lane < NWG)
                        ? __hip_atomic_load(&wgflag[lane * 32], __ATOMIC_RELAXED,
                                            __HIP_MEMORY_SCOPE_AGENT)
                        : t;
                    done = __all(f >= t);
                } while (!done);
            }
            __syncthreads();
            asm volatile("" ::: "memory");
        }

        // --- issue all 16 coherent h loads up-front (ki-major) ---
        i32x4 hv[16];
#pragma unroll
        for (int ki = 0; ki < 16; ki++)
            CLOAD16(hv[ki], hcur + (size_t)b * HH + ki * 32 + q * 8);

        // --- GEMM in 4 chunks, each gated by a register-tied partial wait ---
        f32x4 acc[5] = {};
#define MFMA_CHUNK(KLO)                                                          \
        _Pragma("unroll")                                                        \
        for (int ki = (KLO); ki < (KLO) + 4; ki++) {                             \
            HU u; u.i = hv[ki];                                                  \
            _Pragma("unroll")                                                    \
            for (int g = 0; g < 5; g++) {                                        \
                bf16x8 aw = *(const bf16x8*)&wlds[((g * 16 + ki) * 64 + lane) * 8]; \
                acc[g] = __builtin_amdgcn_mfma_f32_16x16x32_bf16(aw, u.b, acc[g], 0, 0, 0); \
            }                                                                    \
        }
        WAIT4("12", hv[0],  hv[1],  hv[2],  hv[3]);   MFMA_CHUNK(0)
        WAIT4("8",  hv[4],  hv[5],  hv[6],  hv[7]);   MFMA_CHUNK(4)
        WAIT4("4",  hv[8],  hv[9],  hv[10], hv[11]);  MFMA_CHUNK(8)
        WAIT4("0",  hv[12], hv[13], hv[14], hv[15]);  MFMA_CHUNK(12)
#undef MFMA_CHUNK

        // --- epilogue: lane owns batch b x 4 consecutive j ---
        P8 hp;
        float ov4[4];
#pragma unroll
        for (int jj = 0; jj < 4; jj++) {
            const float i_g = sigm(bf2f(pv[0][jj]) + acc[0][jj] + bs[0][jj]);
            const float f_g = sigm(bf2f(pv[1][jj]) + acc[1][jj] + bs[1][jj]);
            const float g_t = tanh_fast(bf2f(pv[2][jj]) + acc[2][jj] + bs[2][jj]);
            const float o_g = sigm(bf2f(pv[3][jj]) + acc[3][jj] + bs[3][jj]);
            const float hw  = sigm(bf2f(pv[4][jj]) + acc[4][jj] + bs[4][jj]);

            float c_new = i_g * g_t + f_g * creg[jj];
            float ov = o_g * tanh_fast(c_new);
            ov = hw * ov + (1.0f - hw) * bf2f(pv[5][jj]);
            if (t >= len) { ov = 0.0f; c_new = 0.0f; }
            creg[jj] = c_new;
            ov4[jj] = ov;
            hp.s[jj] = f2bf(ov);
        }

        // h for next step: coherent 8B store, drain ONLY this before flag
        CSTORE8((void*)(hnxt + (size_t)b * HH + j0 + q * 4), hp.u);
        asm volatile("s_waitcnt vmcnt(0)" ::: "memory");
        __syncthreads();
        if (tid == 0)
            __hip_atomic_store(&wgflag[blockIdx.x * 32], t + 1,
                               __ATOMIC_RELAXED, __HIP_MEMORY_SCOPE_AGENT);

        // --- off-critical-path: output store + projc prefetch for t+1 ---
        if (fp32) {
            float* op = (float*)outv + ((size_t)b * TT + t) * HH + j0 + q * 4;
            *(float4*)op = make_float4(ov4[0], ov4[1], ov4[2], ov4[3]);
        } else {
            unsigned short* op = (unsigned short*)outv + ((size_t)b * TT + t) * HH + j0 + q * 4;
            *(unsigned long long*)op = hp.u;
        }
        const int tln = t - t0 + 1;
        if (tln < Tc) {
            const unsigned short* pb = projc + ((size_t)b * Tc + tln) * SIXH + j0 + q * 4;
#pragma unroll
            for (int g = 0; g < 6; g++) pv[g] = *(const u16x4*)(pb + g * HH);
        }
    }

    // persist c for chunked mode
#pragma unroll
    for (int jj = 0; jj < 4; jj++)
        cbuf[b * HH + j0 + q * 4 + jj] = creg[jj];
}

// ---------------------------------------------------------------------------
extern "C" void kernel_launch(void* const* d_in, const int* in_sizes, int n_in,
                              void* d_out, int out_size, void* d_ws, size_t ws_size,
                              hipStream_t stream) {
    const void* xv      = d_in[0];
    const int*  len     = (const int*)d_in[1];
    const void* w_in    = d_in[2];
    const void* b_in    = d_in[3];
    const void* w_state = d_in[4];
    const void* b_state = d_in[5];

    char* ws = (char*)d_ws;
    int* flags  = (int*)(ws + WS_FLAGS);
    int* wgflag = (int*)(ws + WS_CNT);
    unsigned short* hbuf = (unsigned short*)(ws + WS_H);
    float* cbuf = (float*)(ws + WS_C);
    unsigned short* projc = (unsigned short*)(ws + WS_PROJ);

    // Largest proj chunk (timesteps, power of 2, >= 64) fitting ws.
    int tc_shift = 9;
    while (tc_shift > 6 &&
           WS_PROJ + ((size_t)BB << tc_shift) * SIXH * 2 > ws_size) tc_shift--;
    const int Tc = 1 << tc_shift;

    detect_kernel<<<1, 64, 0, stream>>>((const unsigned short*)xv, len, flags);
    // zero wg flags + h ping-pong + c
    hipMemsetAsync(ws + WS_CNT, 0, WS_PROJ - WS_CNT, stream);

    for (int c = 0; c < TT / Tc; c++) {
        const int t0 = c * Tc;
        proj_kernel<<<dim3(SIXH / 64, (BB << tc_shift) >> 6), 256, 0, stream>>>(
            xv, w_in, b_in, projc, flags, t0, tc_shift);
        rec_kernel<<<NWG, 256, 0, stream>>>(projc, w_state, b_state, len,
                                            hbuf, cbuf, wgflag, d_out, flags, t0, Tc);
    }
}